// Round 9
// baseline (149.825 us; speedup 1.0000x reference)
//
#include <hip/hip_runtime.h>
#include <hip/hip_bf16.h>

#define ALPHA 0.9f
#define BETA  0.85f
#define TSIM  50
#define BATCH 128
#define N0    1024
#define N1    2048
#define N2    2048
#define N3    512

// alpha^50, beta^50, 1/(alpha-beta)
#define A50   0.00515379f
#define B50   0.000295764f
#define INVAB 20.0f

typedef __attribute__((ext_vector_type(8))) short bf16x8;
typedef __attribute__((ext_vector_type(8))) unsigned short ushort8;
typedef __attribute__((ext_vector_type(4))) float f32x4;

#define GLOBAL_AS __attribute__((address_space(1)))
#define LDS_AS    __attribute__((address_space(3)))

// preprocessor repeat lists (t = literal timestep)
#define R32(X) X(0) X(1) X(2) X(3) X(4) X(5) X(6) X(7) X(8) X(9) X(10) X(11) \
               X(12) X(13) X(14) X(15) X(16) X(17) X(18) X(19) X(20) X(21)   \
               X(22) X(23) X(24) X(25) X(26) X(27) X(28) X(29) X(30) X(31)
#define R18(X) X(32) X(33) X(34) X(35) X(36) X(37) X(38) X(39) X(40) X(41)   \
               X(42) X(43) X(44) X(45) X(46) X(47) X(48) X(49)
#define R50(X) R32(X) R18(X)

#define DECLC(t)   float c##t = 0.f;
// Round 25: select-of-constants probes on READFIRSTLANE'd masks. R7 proved
// the select form regresses when the mask sits in a VGPR (v_cndmask chain);
// masks are block-uniform (same address for all threads), so readfirstlane
// legally moves them to SGPRs -> uniform condition -> s_and/s_cselect (SALU,
// co-issues) + 1 v_fmac with SGPR multiplicand = 1 VALU/t vs cvt form's 3.
// Values are exactly w*{0,1}, same order -> bit-identical.
#define PROBELO(t) c##t += ((((lo) >> (t)) & 1u) ? 1.0f : 0.0f) * w;
#define PROBEHI(t) c##t += ((((hi) >> ((t) - 32)) & 1u) ? 1.0f : 0.0f) * w;
#define PROBE4LO(t) c##t += ((((lo0) >> (t)) & 1u) ? 1.0f : 0.0f) * w0; \
                    c##t += ((((lo1) >> (t)) & 1u) ? 1.0f : 0.0f) * w1; \
                    c##t += ((((lo2) >> (t)) & 1u) ? 1.0f : 0.0f) * w2; \
                    c##t += ((((lo3) >> (t)) & 1u) ? 1.0f : 0.0f) * w3;
#define PROBE4HI(t) c##t += ((((hi0) >> ((t) - 32)) & 1u) ? 1.0f : 0.0f) * w0; \
                    c##t += ((((hi1) >> ((t) - 32)) & 1u) ? 1.0f : 0.0f) * w1; \
                    c##t += ((((hi2) >> ((t) - 32)) & 1u) ? 1.0f : 0.0f) * w2; \
                    c##t += ((((hi3) >> ((t) - 32)) & 1u) ? 1.0f : 0.0f) * w3;
#define STEPT(t)                                                  \
    s = ALPHA * s + (base + c##t);                                \
    m = BETA * m + s;                                             \
    if (m - 1.f > 0.f) { a2 += (pa - pb) * INVAB; m = 0.f; }      \
    pa *= inva;                                                   \
    pb *= invb;

// ---------------------------------------------------------------------------
// Split-K fp32 tiled GEMM (layer 0 only). Round 16: do NOT lower split-K.
// Round 18: layer 0 must stay fp32-exact (split-bf16 -> absmax 636 fail).
// Round 22: float4 LDS reads re-applied (inferred ~4us win; As [16][68]).
// ---------------------------------------------------------------------------
__global__ __launch_bounds__(256) void gemm_f32_splitk(const float* __restrict__ A,
                                                       const float* __restrict__ B,
                                                       float* __restrict__ Cp,
                                                       int M, int N, int K, int KC) {
    __shared__ float As[16][68];
    __shared__ float Bs[16][68];

    const int tid = threadIdx.x;
    const int tx  = tid % 16;
    const int ty  = tid / 16;
    const int bx  = blockIdx.x;
    const int by  = blockIdx.y;
    const int z   = blockIdx.z;

    float acc[4][4] = {};

    const int ar = tid / 4;
    const int ak = (tid % 4) * 4;
    const int br = tid / 16;
    const int bc = (tid % 16) * 4;

    const int kbeg = z * KC;
    for (int k0 = kbeg; k0 < kbeg + KC; k0 += 16) {
        float4 av = *(const float4*)&A[(size_t)(by * 64 + ar) * K + k0 + ak];
        As[ak + 0][ar] = av.x;
        As[ak + 1][ar] = av.y;
        As[ak + 2][ar] = av.z;
        As[ak + 3][ar] = av.w;
        float4 bv = *(const float4*)&B[(size_t)(k0 + br) * N + bx * 64 + bc];
        *(float4*)&Bs[br][bc] = bv;
        __syncthreads();

#pragma unroll
        for (int kk = 0; kk < 16; ++kk) {
            const float4 a  = *(const float4*)&As[kk][ty * 4];
            const float4 bq = *(const float4*)&Bs[kk][tx * 4];
            const float a0 = a.x, a1 = a.y, a2 = a.z, a3 = a.w;
            const float b0 = bq.x, b1 = bq.y, b2 = bq.z, b3 = bq.w;
            acc[0][0] += a0 * b0; acc[0][1] += a0 * b1; acc[0][2] += a0 * b2; acc[0][3] += a0 * b3;
            acc[1][0] += a1 * b0; acc[1][1] += a1 * b1; acc[1][2] += a1 * b2; acc[1][3] += a1 * b3;
            acc[2][0] += a2 * b0; acc[2][1] += a2 * b1; acc[2][2] += a2 * b2; acc[2][3] += a2 * b3;
            acc[3][0] += a3 * b0; acc[3][1] += a3 * b1; acc[3][2] += a3 * b2; acc[3][3] += a3 * b3;
        }
        __syncthreads();
    }

#pragma unroll
    for (int i = 0; i < 4; ++i) {
        float4 v = make_float4(acc[i][0], acc[i][1], acc[i][2], acc[i][3]);
        *(float4*)&Cp[((size_t)z * M + by * 64 + ty * 4 + i) * N + bx * 64 + tx * 4] = v;
    }
}

// ---------------------------------------------------------------------------
// Layer-0 simulate + classify (sums 8 split-K partials; deterministic
// per-(b,chunk) residual lists via wave ballot + LDS wave-count scan).
// ---------------------------------------------------------------------------
__global__ __launch_bounds__(256) void scan_l0_classify(const float* __restrict__ P0,
                                                        __hip_bfloat16* __restrict__ C0,
                                                        int* __restrict__ jlist0,
                                                        unsigned long long* __restrict__ mask0,
                                                        int* __restrict__ count0) {
    const int b     = blockIdx.x;
    const int chunk = blockIdx.y;
    const int tid   = threadIdx.x;
    const int j     = chunk * 256 + tid;
    const int lane  = tid & 63;
    const int wv    = tid >> 6;

    float h = 0.f;
#pragma unroll
    for (int z = 0; z < 8; ++z) h += P0[((size_t)z * BATCH + b) * N1 + j];

    float m = 0.f;
    unsigned long long mask = 0ull;
#pragma unroll
    for (int t = 0; t < TSIM; ++t) {
        m = BETA * m + h;
        if (m - 1.f > 0.f) { mask |= (1ull << t); m = 0.f; }
    }
    const unsigned long long FULL = (1ull << TSIM) - 1ull;
    C0[(size_t)b * N1 + j] = __float2bfloat16((mask == FULL) ? 1.f : 0.f);

    const bool has = (mask != 0ull) && (mask != FULL);
    const unsigned long long bal = __ballot(has);

    __shared__ int wcnt[4];
    if (lane == 0) wcnt[wv] = __popcll(bal);
    __syncthreads();
    int base = 0;
#pragma unroll
    for (int w = 0; w < 4; ++w)
        if (w < wv) base += wcnt[w];
    const int pos = base + __popcll(bal & ((1ull << lane) - 1ull));

    const size_t lbase = (size_t)(b * 8 + chunk) * 256;
    if (has) {
        jlist0[lbase + pos] = j;
        mask0[lbase + pos]  = mask;
    }
    if (tid == 0) count0[b * 8 + chunk] = wcnt[0] + wcnt[1] + wcnt[2] + wcnt[3];
}

// ---------------------------------------------------------------------------
// MFMA GEMM (BN=64, BM=128=M, BK=32; 4 waves stacked in M; WMT=2, WNT=4):
// Cp[z] = C0 @ (W1h+W1l)^T, split-K 16 (KC=128, 512 blocks).
// W1 transpose + hi/lo split fused into B-staging (round 17, verified win).
// ---------------------------------------------------------------------------
__global__ __launch_bounds__(256) void gemm3_bn64_fused(const __hip_bfloat16* __restrict__ A,
                                                        const float* __restrict__ W, // (N1, N2) fp32
                                                        float* __restrict__ Cp, int KC) {
    __shared__ alignas(16) __hip_bfloat16 As[128 * 32];
    __shared__ alignas(16) __hip_bfloat16 Bhs[64 * 32];
    __shared__ alignas(16) __hip_bfloat16 Bls[64 * 32];

    constexpr int BK = 32;
    const int M = BATCH, N = N2, K = N1;

    const int tid  = threadIdx.x;
    const int wave = tid >> 6;
    const int lane = tid & 63;
    const int quad = lane >> 4;
    const int l16  = lane & 15;

    const int n0 = blockIdx.x * 64;
    const int z  = blockIdx.y;
    const int wm = wave * 32;

    f32x4 acc[2][4] = {};

    const __hip_bfloat16* agp[2];
    int aoff[2];
#pragma unroll
    for (int i = 0; i < 2; ++i) {
        const int c = i * 256 + tid;
        agp[i]  = A + (size_t)(c >> 2) * K + (c & 3) * 8;
        aoff[i] = c * 8;
    }

    // fused B staging: this thread owns col n0+bn, rows k0+bkb..k0+bkb+7
    const int bn  = tid >> 2;        // 0..63
    const int bkb = (tid & 3) * 8;   // 0,8,16,24

    const int kbeg = z * KC;
    for (int k0 = kbeg; k0 < kbeg + KC; k0 += BK) {
#pragma unroll
        for (int i = 0; i < 2; ++i)
            __builtin_amdgcn_global_load_lds((const GLOBAL_AS void*)(agp[i] + k0),
                                             (LDS_AS void*)&As[aoff[i]], 16, 0, 0);

        float wv[8];
#pragma unroll
        for (int u = 0; u < 8; ++u)
            wv[u] = W[(size_t)(k0 + bkb + u) * N + n0 + bn];

        ushort8 vh, vl;
#pragma unroll
        for (int u = 0; u < 8; ++u) {
            const float w = wv[u];
            const __hip_bfloat16 hi = __float2bfloat16(w);
            const float lo = w - __bfloat162float(hi);
            const __hip_bfloat16 lb = __float2bfloat16(lo);
            vh[u] = *(const unsigned short*)&hi;
            vl[u] = *(const unsigned short*)&lb;
        }
        *(ushort8*)&Bhs[bn * BK + bkb] = vh;
        *(ushort8*)&Bls[bn * BK + bkb] = vl;
        __syncthreads();

        bf16x8 af[2], bhf[4], blf[4];
#pragma unroll
        for (int i = 0; i < 2; ++i)
            af[i] = *(const bf16x8*)&As[(wm + i * 16 + l16) * BK + quad * 8];
#pragma unroll
        for (int j = 0; j < 4; ++j) {
            bhf[j] = *(const bf16x8*)&Bhs[(j * 16 + l16) * BK + quad * 8];
            blf[j] = *(const bf16x8*)&Bls[(j * 16 + l16) * BK + quad * 8];
        }
#pragma unroll
        for (int i = 0; i < 2; ++i)
#pragma unroll
            for (int j = 0; j < 4; ++j) {
                acc[i][j] = __builtin_amdgcn_mfma_f32_16x16x32_bf16(af[i], bhf[j], acc[i][j], 0, 0, 0);
                acc[i][j] = __builtin_amdgcn_mfma_f32_16x16x32_bf16(af[i], blf[j], acc[i][j], 0, 0, 0);
            }
        __syncthreads();
    }

    // C/D layout: col = lane&15, row = quad*4 + reg
#pragma unroll
    for (int i = 0; i < 2; ++i)
#pragma unroll
        for (int j = 0; j < 4; ++j)
#pragma unroll
            for (int r = 0; r < 4; ++r)
                Cp[((size_t)z * M + wm + i * 16 + quad * 4 + r) * N + n0 + j * 16 + l16] =
                    acc[i][j][r];
}

// ---------------------------------------------------------------------------
// Round 22: layer-2 GEMM MFMA split-bf16 3-product (verified pass, absmax 32).
// PB2[z] = A2 @ W2 chunk z. BM=128(=M), BN=32, BK=32, split-K 16, 256 blocks.
// ---------------------------------------------------------------------------
__global__ __launch_bounds__(256) void gemm2_mfma(const float* __restrict__ A,  // (128,2048)
                                                  const float* __restrict__ W,  // (2048,512)
                                                  float* __restrict__ Cp, int KC) {
    __shared__ alignas(16) __hip_bfloat16 Ahs[128 * 32];
    __shared__ alignas(16) __hip_bfloat16 Als[128 * 32];
    __shared__ alignas(16) __hip_bfloat16 Bhs[32 * 32];
    __shared__ alignas(16) __hip_bfloat16 Bls[32 * 32];

    constexpr int BK = 32;
    const int tid  = threadIdx.x;
    const int wave = tid >> 6;
    const int lane = tid & 63;
    const int quad = lane >> 4;
    const int l16  = lane & 15;

    const int n0 = blockIdx.x * 32;
    const int z  = blockIdx.y;
    const int wm = wave * 32;

    f32x4 acc[2][2] = {};

    const int ar = tid >> 1;
    const int ao = (tid & 1) * 16;
    const int bn = tid & 31;
    const int bq = (tid >> 5) * 4;

    const int kbeg = z * KC;
    for (int k0 = kbeg; k0 < kbeg + KC; k0 += BK) {
        float af[16];
#pragma unroll
        for (int q = 0; q < 4; ++q) {
            float4 v = *(const float4*)&A[(size_t)ar * N2 + k0 + ao + q * 4];
            af[q * 4 + 0] = v.x; af[q * 4 + 1] = v.y;
            af[q * 4 + 2] = v.z; af[q * 4 + 3] = v.w;
        }
#pragma unroll
        for (int h = 0; h < 2; ++h) {
            ushort8 vh, vl;
#pragma unroll
            for (int u = 0; u < 8; ++u) {
                const float a = af[h * 8 + u];
                const __hip_bfloat16 hi = __float2bfloat16(a);
                const float lo = a - __bfloat162float(hi);
                const __hip_bfloat16 lb = __float2bfloat16(lo);
                vh[u] = *(const unsigned short*)&hi;
                vl[u] = *(const unsigned short*)&lb;
            }
            *(ushort8*)&Ahs[ar * BK + ao + h * 8] = vh;
            *(ushort8*)&Als[ar * BK + ao + h * 8] = vl;
        }

        {
            float wf[4];
#pragma unroll
            for (int u = 0; u < 4; ++u)
                wf[u] = W[(size_t)(k0 + bq + u) * N3 + n0 + bn];
#pragma unroll
            for (int u = 0; u < 4; ++u) {
                const float w = wf[u];
                const __hip_bfloat16 hi = __float2bfloat16(w);
                const float lo = w - __bfloat162float(hi);
                const __hip_bfloat16 lb = __float2bfloat16(lo);
                Bhs[bn * BK + bq + u] = hi;
                Bls[bn * BK + bq + u] = lb;
            }
        }
        __syncthreads();

        bf16x8 ah[2], al[2], bh[2], bl[2];
#pragma unroll
        for (int i = 0; i < 2; ++i) {
            ah[i] = *(const bf16x8*)&Ahs[(wm + i * 16 + l16) * BK + quad * 8];
            al[i] = *(const bf16x8*)&Als[(wm + i * 16 + l16) * BK + quad * 8];
        }
#pragma unroll
        for (int j = 0; j < 2; ++j) {
            bh[j] = *(const bf16x8*)&Bhs[(j * 16 + l16) * BK + quad * 8];
            bl[j] = *(const bf16x8*)&Bls[(j * 16 + l16) * BK + quad * 8];
        }
#pragma unroll
        for (int i = 0; i < 2; ++i)
#pragma unroll
            for (int j = 0; j < 2; ++j) {
                acc[i][j] = __builtin_amdgcn_mfma_f32_16x16x32_bf16(ah[i], bh[j], acc[i][j], 0, 0, 0);
                acc[i][j] = __builtin_amdgcn_mfma_f32_16x16x32_bf16(ah[i], bl[j], acc[i][j], 0, 0, 0);
                acc[i][j] = __builtin_amdgcn_mfma_f32_16x16x32_bf16(al[i], bh[j], acc[i][j], 0, 0, 0);
            }
        __syncthreads();
    }

#pragma unroll
    for (int i = 0; i < 2; ++i)
#pragma unroll
        for (int j = 0; j < 2; ++j)
#pragma unroll
            for (int r = 0; r < 4; ++r)
                Cp[((size_t)z * BATCH + wm + i * 16 + quad * 4 + r) * N3 + n0 + j * 16 + l16] =
                    acc[i][j][r];
}

// ---------------------------------------------------------------------------
// Layer-1 fused drive + membrane scan + linear layer-2 projection.
// 50 named scalar accumulators + __launch_bounds__(256,2): do not lower.
// Lever scoreboard: batch-4 WIN; batch-8 neutral; VGPR-select ✗ (R7 +6.6);
// prefetch ✗ (R19); LDS list-stage ✗ (R8 +2.2; reverted here).
// R25: masks/indices are block-uniform -> readfirstlane to SGPR, select form
// now scalarizes (s_cselect + v_fmac = 1 VALU/t). Bit-identical.
// ---------------------------------------------------------------------------
__global__ __launch_bounds__(256, 2) void h1_scan_a2(const float* __restrict__ PB1,
                                                     const float* __restrict__ W1,
                                                     const int* __restrict__ jlist0,
                                                     const unsigned long long* __restrict__ mask0,
                                                     const int* __restrict__ count0,
                                                     float* __restrict__ A2) {
    const int b  = blockIdx.x;
    const int jc = blockIdx.y * 256 + threadIdx.x;

    float base = 0.f;
#pragma unroll
    for (int z = 0; z < 16; ++z) base += PB1[((size_t)z * BATCH + b) * N2 + jc];

    R50(DECLC)

    for (int c = 0; c < 8; ++c) {
        const int cnt      = count0[b * 8 + c];
        const size_t lbase = (size_t)(b * 8 + c) * 256;
        int e = 0;
        for (; e + 4 <= cnt; e += 4) {
            const int j0 = __builtin_amdgcn_readfirstlane(jlist0[lbase + e + 0]);
            const int j1 = __builtin_amdgcn_readfirstlane(jlist0[lbase + e + 1]);
            const int j2 = __builtin_amdgcn_readfirstlane(jlist0[lbase + e + 2]);
            const int j3 = __builtin_amdgcn_readfirstlane(jlist0[lbase + e + 3]);
            const float w0 = W1[(size_t)j0 * N2 + jc];
            const float w1 = W1[(size_t)j1 * N2 + jc];
            const float w2 = W1[(size_t)j2 * N2 + jc];
            const float w3 = W1[(size_t)j3 * N2 + jc];
            const unsigned long long ma = mask0[lbase + e + 0];
            const unsigned long long mb = mask0[lbase + e + 1];
            const unsigned long long mc = mask0[lbase + e + 2];
            const unsigned long long md = mask0[lbase + e + 3];
            const unsigned lo0 = __builtin_amdgcn_readfirstlane((unsigned)ma);
            const unsigned hi0 = __builtin_amdgcn_readfirstlane((unsigned)(ma >> 32));
            const unsigned lo1 = __builtin_amdgcn_readfirstlane((unsigned)mb);
            const unsigned hi1 = __builtin_amdgcn_readfirstlane((unsigned)(mb >> 32));
            const unsigned lo2 = __builtin_amdgcn_readfirstlane((unsigned)mc);
            const unsigned hi2 = __builtin_amdgcn_readfirstlane((unsigned)(mc >> 32));
            const unsigned lo3 = __builtin_amdgcn_readfirstlane((unsigned)md);
            const unsigned hi3 = __builtin_amdgcn_readfirstlane((unsigned)(md >> 32));
            R32(PROBE4LO)
            R18(PROBE4HI)
        }
        for (; e < cnt; ++e) {
            const unsigned long long mk = mask0[lbase + e];
            const int j                 = __builtin_amdgcn_readfirstlane(jlist0[lbase + e]);
            const float w               = W1[(size_t)j * N2 + jc];
            const unsigned lo = __builtin_amdgcn_readfirstlane((unsigned)mk);
            const unsigned hi = __builtin_amdgcn_readfirstlane((unsigned)(mk >> 32));
            R32(PROBELO)
            R18(PROBEHI)
        }
    }

    float s = 0.f, m = 0.f, a2 = 0.f;
    float pa = A50, pb = B50;
    const float inva = 1.0f / ALPHA, invb = 1.0f / BETA;
    R50(STEPT)

    A2[(size_t)b * N2 + jc] = a2;
}

// ---------------------------------------------------------------------------
// Sum 16 split-K partials of A2@W2 -> final output (128 x 512).
// ---------------------------------------------------------------------------
__global__ __launch_bounds__(256) void reduce_out(const float* __restrict__ PB2,
                                                  float* __restrict__ out) {
    const int idx = blockIdx.x * 256 + threadIdx.x;
    float v = 0.f;
#pragma unroll
    for (int z = 0; z < 16; ++z) v += PB2[(size_t)z * (BATCH * N3) + idx];
    out[idx] = v;
}

extern "C" void kernel_launch(void* const* d_in, const int* in_sizes, int n_in,
                              void* d_out, int out_size, void* d_ws, size_t ws_size,
                              hipStream_t stream) {
    const float* inputs = (const float*)d_in[0];   // (128, 1024)
    const float* W0     = (const float*)d_in[1];   // (1024, 2048)
    const float* W1     = (const float*)d_in[2];   // (2048, 2048)
    const float* W2     = (const float*)d_in[3];   // (2048, 512)
    float* out = (float*)d_out;                    // (128, 512)

    // workspace layout (~35 MB)
    float* P0  = (float*)d_ws;                         // 8 x 128 x 2048   fp32
    float* PB1 = P0 + 8 * BATCH * N1;                  // 16 x 128 x 2048  fp32
    float* A2  = PB1 + 16 * BATCH * N2;                // 128 x 2048       fp32
    float* PB2 = A2 + BATCH * N2;                      // 16 x 128 x 512   fp32
    unsigned long long* mk0 = (unsigned long long*)(PB2 + 16 * BATCH * N3);  // 128x8x256
    __hip_bfloat16* C0bf = (__hip_bfloat16*)(mk0 + BATCH * 8 * 256);         // 128 x 2048
    int* jl0  = (int*)(C0bf + (size_t)BATCH * N1);                           // 128 x 8 x 256
    int* cnt0 = jl0 + BATCH * 8 * 256;                                       // 128 x 8

    // 1. P0[z] = inputs @ W0 chunks   (128 x 1024 x 2048, split-K 8, fp32 —
    //    round-18 lesson: must stay fp32-exact)
    gemm_f32_splitk<<<dim3(N1 / 64, BATCH / 64, 8), 256, 0, stream>>>(
        inputs, W0, P0, BATCH, N1, N0, N0 / 8);

    // 2. layer-0 simulate + classify -> C0 (bf16), residual lists
    scan_l0_classify<<<dim3(BATCH, N1 / 256), 256, 0, stream>>>(P0, C0bf, jl0, mk0, cnt0);

    // 3. PB1[z] = C0 @ W1 chunks      (128 x 2048 x 2048, split-K 16, MFMA BN=64,
    //    W1 transpose + hi/lo split fused into B-staging)
    gemm3_bn64_fused<<<dim3(N2 / 64, 16), 256, 0, stream>>>(C0bf, W1, PB1, N1 / 16);

    // 4. fused layer-1 drive + scan + linear layer-2 projection -> A2
    h1_scan_a2<<<dim3(BATCH, N2 / 256), 256, 0, stream>>>(
        PB1, W1, jl0, mk0, cnt0, A2);

    // 5. PB2[z] = A2 @ W2 chunks      (128 x 2048 x 512, split-K 16, MFMA
    //    split-bf16 3-product — round 22)
    gemm2_mfma<<<dim3(N3 / 32, 16), 256, 0, stream>>>(A2, W2, PB2, N2 / 16);

    // 6. sum partials -> final membrane (128 x 512)
    reduce_out<<<(BATCH * N3) / 256, 256, 0, stream>>>(PB2, out);
}

// Round 10
// 138.350 us; speedup vs baseline: 1.0829x; 1.0829x over previous
//
#include <hip/hip_runtime.h>
#include <hip/hip_bf16.h>

#define ALPHA 0.9f
#define BETA  0.85f
#define TSIM  50
#define BATCH 128
#define N0    1024
#define N1    2048
#define N2    2048
#define N3    512

// alpha^50, beta^50, 1/(alpha-beta)
#define A50   0.00515379f
#define B50   0.000295764f
#define INVAB 20.0f

typedef __attribute__((ext_vector_type(8))) short bf16x8;
typedef __attribute__((ext_vector_type(8))) unsigned short ushort8;
typedef __attribute__((ext_vector_type(4))) float f32x4;

#define GLOBAL_AS __attribute__((address_space(1)))
#define LDS_AS    __attribute__((address_space(3)))

#define DECLC(t)   float c##t = 0.f;
#define R32(X) X(0) X(1) X(2) X(3) X(4) X(5) X(6) X(7) X(8) X(9) X(10) X(11) \
               X(12) X(13) X(14) X(15) X(16) X(17) X(18) X(19) X(20) X(21)   \
               X(22) X(23) X(24) X(25) X(26) X(27) X(28) X(29) X(30) X(31)
#define R18(X) X(32) X(33) X(34) X(35) X(36) X(37) X(38) X(39) X(40) X(41)   \
               X(42) X(43) X(44) X(45) X(46) X(47) X(48) X(49)
#define R50(X) R32(X) R18(X)

#define STEPT(t)                                                  \
    s = ALPHA * s + (base + c##t);                                \
    m = BETA * m + s;                                             \
    if (m - 1.f > 0.f) { a2 += (pa - pb) * INVAB; m = 0.f; }      \
    pa *= inva;                                                   \
    pb *= invb;

// Round 26 probe macros: bits pre-converted to floats in LDS (block-shared),
// read via broadcast ds_read_b128 (uniform addr = conflict-free). Values are
// exactly {0.0,1.0}*w in the same per-c##t order (e ascending) as the proven
// cvt form -> bit-identical.
// 4-entry group, t0..t3 = consecutive literal timesteps (t0 % 4 == 0):
#define PQ4(t0,t1,t2,t3) \
    { const float4 q0 = *(const float4*)&bitsf[eo0 + t0]; \
      const float4 q1 = *(const float4*)&bitsf[eo1 + t0]; \
      const float4 q2 = *(const float4*)&bitsf[eo2 + t0]; \
      const float4 q3 = *(const float4*)&bitsf[eo3 + t0]; \
      c##t0 += w0 * q0.x; c##t0 += w1 * q1.x; c##t0 += w2 * q2.x; c##t0 += w3 * q3.x; \
      c##t1 += w0 * q0.y; c##t1 += w1 * q1.y; c##t1 += w2 * q2.y; c##t1 += w3 * q3.y; \
      c##t2 += w0 * q0.z; c##t2 += w1 * q1.z; c##t2 += w2 * q2.z; c##t2 += w3 * q3.z; \
      c##t3 += w0 * q0.w; c##t3 += w1 * q1.w; c##t3 += w2 * q2.w; c##t3 += w3 * q3.w; }
// single-entry variant:
#define PS4(t0,t1,t2,t3) \
    { const float4 q = *(const float4*)&bitsf[eo + t0]; \
      c##t0 += w * q.x; c##t1 += w * q.y; c##t2 += w * q.z; c##t3 += w * q.w; }

// ---------------------------------------------------------------------------
// Split-K fp32 tiled GEMM (layer 0 only). Round 16: do NOT lower split-K.
// Round 18: layer 0 must stay fp32-exact (split-bf16 -> absmax 636 fail).
// Round 22: float4 LDS reads (As [16][68], 2x ds_read_b128 per kk).
// ---------------------------------------------------------------------------
__global__ __launch_bounds__(256) void gemm_f32_splitk(const float* __restrict__ A,
                                                       const float* __restrict__ B,
                                                       float* __restrict__ Cp,
                                                       int M, int N, int K, int KC) {
    __shared__ float As[16][68];
    __shared__ float Bs[16][68];

    const int tid = threadIdx.x;
    const int tx  = tid % 16;
    const int ty  = tid / 16;
    const int bx  = blockIdx.x;
    const int by  = blockIdx.y;
    const int z   = blockIdx.z;

    float acc[4][4] = {};

    const int ar = tid / 4;
    const int ak = (tid % 4) * 4;
    const int br = tid / 16;
    const int bc = (tid % 16) * 4;

    const int kbeg = z * KC;
    for (int k0 = kbeg; k0 < kbeg + KC; k0 += 16) {
        float4 av = *(const float4*)&A[(size_t)(by * 64 + ar) * K + k0 + ak];
        As[ak + 0][ar] = av.x;
        As[ak + 1][ar] = av.y;
        As[ak + 2][ar] = av.z;
        As[ak + 3][ar] = av.w;
        float4 bv = *(const float4*)&B[(size_t)(k0 + br) * N + bx * 64 + bc];
        *(float4*)&Bs[br][bc] = bv;
        __syncthreads();

#pragma unroll
        for (int kk = 0; kk < 16; ++kk) {
            const float4 a  = *(const float4*)&As[kk][ty * 4];
            const float4 bq = *(const float4*)&Bs[kk][tx * 4];
            const float a0 = a.x, a1 = a.y, a2 = a.z, a3 = a.w;
            const float b0 = bq.x, b1 = bq.y, b2 = bq.z, b3 = bq.w;
            acc[0][0] += a0 * b0; acc[0][1] += a0 * b1; acc[0][2] += a0 * b2; acc[0][3] += a0 * b3;
            acc[1][0] += a1 * b0; acc[1][1] += a1 * b1; acc[1][2] += a1 * b2; acc[1][3] += a1 * b3;
            acc[2][0] += a2 * b0; acc[2][1] += a2 * b1; acc[2][2] += a2 * b2; acc[2][3] += a2 * b3;
            acc[3][0] += a3 * b0; acc[3][1] += a3 * b1; acc[3][2] += a3 * b2; acc[3][3] += a3 * b3;
        }
        __syncthreads();
    }

#pragma unroll
    for (int i = 0; i < 4; ++i) {
        float4 v = make_float4(acc[i][0], acc[i][1], acc[i][2], acc[i][3]);
        *(float4*)&Cp[((size_t)z * M + by * 64 + ty * 4 + i) * N + bx * 64 + tx * 4] = v;
    }
}

// ---------------------------------------------------------------------------
// Layer-0 simulate + classify (sums 8 split-K partials; deterministic
// per-(b,chunk) residual lists via wave ballot + LDS wave-count scan).
// ---------------------------------------------------------------------------
__global__ __launch_bounds__(256) void scan_l0_classify(const float* __restrict__ P0,
                                                        __hip_bfloat16* __restrict__ C0,
                                                        int* __restrict__ jlist0,
                                                        unsigned long long* __restrict__ mask0,
                                                        int* __restrict__ count0) {
    const int b     = blockIdx.x;
    const int chunk = blockIdx.y;
    const int tid   = threadIdx.x;
    const int j     = chunk * 256 + tid;
    const int lane  = tid & 63;
    const int wv    = tid >> 6;

    float h = 0.f;
#pragma unroll
    for (int z = 0; z < 8; ++z) h += P0[((size_t)z * BATCH + b) * N1 + j];

    float m = 0.f;
    unsigned long long mask = 0ull;
#pragma unroll
    for (int t = 0; t < TSIM; ++t) {
        m = BETA * m + h;
        if (m - 1.f > 0.f) { mask |= (1ull << t); m = 0.f; }
    }
    const unsigned long long FULL = (1ull << TSIM) - 1ull;
    C0[(size_t)b * N1 + j] = __float2bfloat16((mask == FULL) ? 1.f : 0.f);

    const bool has = (mask != 0ull) && (mask != FULL);
    const unsigned long long bal = __ballot(has);

    __shared__ int wcnt[4];
    if (lane == 0) wcnt[wv] = __popcll(bal);
    __syncthreads();
    int base = 0;
#pragma unroll
    for (int w = 0; w < 4; ++w)
        if (w < wv) base += wcnt[w];
    const int pos = base + __popcll(bal & ((1ull << lane) - 1ull));

    const size_t lbase = (size_t)(b * 8 + chunk) * 256;
    if (has) {
        jlist0[lbase + pos] = j;
        mask0[lbase + pos]  = mask;
    }
    if (tid == 0) count0[b * 8 + chunk] = wcnt[0] + wcnt[1] + wcnt[2] + wcnt[3];
}

// ---------------------------------------------------------------------------
// MFMA GEMM (BN=64, BM=128=M, BK=32; 4 waves stacked in M; WMT=2, WNT=4):
// Cp[z] = C0 @ (W1h+W1l)^T, split-K 16 (KC=128, 512 blocks).
// W1 transpose + hi/lo split fused into B-staging (round 17, verified win).
// ---------------------------------------------------------------------------
__global__ __launch_bounds__(256) void gemm3_bn64_fused(const __hip_bfloat16* __restrict__ A,
                                                        const float* __restrict__ W, // (N1, N2) fp32
                                                        float* __restrict__ Cp, int KC) {
    __shared__ alignas(16) __hip_bfloat16 As[128 * 32];
    __shared__ alignas(16) __hip_bfloat16 Bhs[64 * 32];
    __shared__ alignas(16) __hip_bfloat16 Bls[64 * 32];

    constexpr int BK = 32;
    const int M = BATCH, N = N2, K = N1;

    const int tid  = threadIdx.x;
    const int wave = tid >> 6;
    const int lane = tid & 63;
    const int quad = lane >> 4;
    const int l16  = lane & 15;

    const int n0 = blockIdx.x * 64;
    const int z  = blockIdx.y;
    const int wm = wave * 32;

    f32x4 acc[2][4] = {};

    const __hip_bfloat16* agp[2];
    int aoff[2];
#pragma unroll
    for (int i = 0; i < 2; ++i) {
        const int c = i * 256 + tid;
        agp[i]  = A + (size_t)(c >> 2) * K + (c & 3) * 8;
        aoff[i] = c * 8;
    }

    // fused B staging: this thread owns col n0+bn, rows k0+bkb..k0+bkb+7
    const int bn  = tid >> 2;        // 0..63
    const int bkb = (tid & 3) * 8;   // 0,8,16,24

    const int kbeg = z * KC;
    for (int k0 = kbeg; k0 < kbeg + KC; k0 += BK) {
#pragma unroll
        for (int i = 0; i < 2; ++i)
            __builtin_amdgcn_global_load_lds((const GLOBAL_AS void*)(agp[i] + k0),
                                             (LDS_AS void*)&As[aoff[i]], 16, 0, 0);

        float wv[8];
#pragma unroll
        for (int u = 0; u < 8; ++u)
            wv[u] = W[(size_t)(k0 + bkb + u) * N + n0 + bn];

        ushort8 vh, vl;
#pragma unroll
        for (int u = 0; u < 8; ++u) {
            const float w = wv[u];
            const __hip_bfloat16 hi = __float2bfloat16(w);
            const float lo = w - __bfloat162float(hi);
            const __hip_bfloat16 lb = __float2bfloat16(lo);
            vh[u] = *(const unsigned short*)&hi;
            vl[u] = *(const unsigned short*)&lb;
        }
        *(ushort8*)&Bhs[bn * BK + bkb] = vh;
        *(ushort8*)&Bls[bn * BK + bkb] = vl;
        __syncthreads();

        bf16x8 af[2], bhf[4], blf[4];
#pragma unroll
        for (int i = 0; i < 2; ++i)
            af[i] = *(const bf16x8*)&As[(wm + i * 16 + l16) * BK + quad * 8];
#pragma unroll
        for (int j = 0; j < 4; ++j) {
            bhf[j] = *(const bf16x8*)&Bhs[(j * 16 + l16) * BK + quad * 8];
            blf[j] = *(const bf16x8*)&Bls[(j * 16 + l16) * BK + quad * 8];
        }
#pragma unroll
        for (int i = 0; i < 2; ++i)
#pragma unroll
            for (int j = 0; j < 4; ++j) {
                acc[i][j] = __builtin_amdgcn_mfma_f32_16x16x32_bf16(af[i], bhf[j], acc[i][j], 0, 0, 0);
                acc[i][j] = __builtin_amdgcn_mfma_f32_16x16x32_bf16(af[i], blf[j], acc[i][j], 0, 0, 0);
            }
        __syncthreads();
    }

    // C/D layout: col = lane&15, row = quad*4 + reg
#pragma unroll
    for (int i = 0; i < 2; ++i)
#pragma unroll
        for (int j = 0; j < 4; ++j)
#pragma unroll
            for (int r = 0; r < 4; ++r)
                Cp[((size_t)z * M + wm + i * 16 + quad * 4 + r) * N + n0 + j * 16 + l16] =
                    acc[i][j][r];
}

// ---------------------------------------------------------------------------
// Round 22: layer-2 GEMM MFMA split-bf16 3-product (verified pass, absmax 32).
// PB2[z] = A2 @ W2 chunk z. BM=128(=M), BN=32, BK=32, split-K 16, 256 blocks.
// ---------------------------------------------------------------------------
__global__ __launch_bounds__(256) void gemm2_mfma(const float* __restrict__ A,  // (128,2048)
                                                  const float* __restrict__ W,  // (2048,512)
                                                  float* __restrict__ Cp, int KC) {
    __shared__ alignas(16) __hip_bfloat16 Ahs[128 * 32];
    __shared__ alignas(16) __hip_bfloat16 Als[128 * 32];
    __shared__ alignas(16) __hip_bfloat16 Bhs[32 * 32];
    __shared__ alignas(16) __hip_bfloat16 Bls[32 * 32];

    constexpr int BK = 32;
    const int tid  = threadIdx.x;
    const int wave = tid >> 6;
    const int lane = tid & 63;
    const int quad = lane >> 4;
    const int l16  = lane & 15;

    const int n0 = blockIdx.x * 32;
    const int z  = blockIdx.y;
    const int wm = wave * 32;

    f32x4 acc[2][2] = {};

    const int ar = tid >> 1;
    const int ao = (tid & 1) * 16;
    const int bn = tid & 31;
    const int bq = (tid >> 5) * 4;

    const int kbeg = z * KC;
    for (int k0 = kbeg; k0 < kbeg + KC; k0 += BK) {
        float af[16];
#pragma unroll
        for (int q = 0; q < 4; ++q) {
            float4 v = *(const float4*)&A[(size_t)ar * N2 + k0 + ao + q * 4];
            af[q * 4 + 0] = v.x; af[q * 4 + 1] = v.y;
            af[q * 4 + 2] = v.z; af[q * 4 + 3] = v.w;
        }
#pragma unroll
        for (int h = 0; h < 2; ++h) {
            ushort8 vh, vl;
#pragma unroll
            for (int u = 0; u < 8; ++u) {
                const float a = af[h * 8 + u];
                const __hip_bfloat16 hi = __float2bfloat16(a);
                const float lo = a - __bfloat162float(hi);
                const __hip_bfloat16 lb = __float2bfloat16(lo);
                vh[u] = *(const unsigned short*)&hi;
                vl[u] = *(const unsigned short*)&lb;
            }
            *(ushort8*)&Ahs[ar * BK + ao + h * 8] = vh;
            *(ushort8*)&Als[ar * BK + ao + h * 8] = vl;
        }

        {
            float wf[4];
#pragma unroll
            for (int u = 0; u < 4; ++u)
                wf[u] = W[(size_t)(k0 + bq + u) * N3 + n0 + bn];
#pragma unroll
            for (int u = 0; u < 4; ++u) {
                const float w = wf[u];
                const __hip_bfloat16 hi = __float2bfloat16(w);
                const float lo = w - __bfloat162float(hi);
                const __hip_bfloat16 lb = __float2bfloat16(lo);
                Bhs[bn * BK + bq + u] = hi;
                Bls[bn * BK + bq + u] = lb;
            }
        }
        __syncthreads();

        bf16x8 ah[2], al[2], bh[2], bl[2];
#pragma unroll
        for (int i = 0; i < 2; ++i) {
            ah[i] = *(const bf16x8*)&Ahs[(wm + i * 16 + l16) * BK + quad * 8];
            al[i] = *(const bf16x8*)&Als[(wm + i * 16 + l16) * BK + quad * 8];
        }
#pragma unroll
        for (int j = 0; j < 2; ++j) {
            bh[j] = *(const bf16x8*)&Bhs[(j * 16 + l16) * BK + quad * 8];
            bl[j] = *(const bf16x8*)&Bls[(j * 16 + l16) * BK + quad * 8];
        }
#pragma unroll
        for (int i = 0; i < 2; ++i)
#pragma unroll
            for (int j = 0; j < 2; ++j) {
                acc[i][j] = __builtin_amdgcn_mfma_f32_16x16x32_bf16(ah[i], bh[j], acc[i][j], 0, 0, 0);
                acc[i][j] = __builtin_amdgcn_mfma_f32_16x16x32_bf16(ah[i], bl[j], acc[i][j], 0, 0, 0);
                acc[i][j] = __builtin_amdgcn_mfma_f32_16x16x32_bf16(al[i], bh[j], acc[i][j], 0, 0, 0);
            }
        __syncthreads();
    }

#pragma unroll
    for (int i = 0; i < 2; ++i)
#pragma unroll
        for (int j = 0; j < 2; ++j)
#pragma unroll
            for (int r = 0; r < 4; ++r)
                Cp[((size_t)z * BATCH + wm + i * 16 + quad * 4 + r) * N3 + n0 + j * 16 + l16] =
                    acc[i][j][r];
}

// ---------------------------------------------------------------------------
// Layer-1 fused drive + membrane scan + linear layer-2 projection.
// Lever scoreboard: batch-4 WIN; batch-8 ~; select ✗✗ (R7 VGPR +6.6, R9 SGPR
// +13 — SALU does NOT co-issue with VALU from the same wave; instruction
// COUNT is what matters); prefetch ✗; LDS list-stage ✗.
// Round 26: block-shared bit->float staging. The cvt work (redundant 256x per
// block) is done once into LDS; probes read via broadcast ds_read_b128
// (uniform addr, conflict-free) + fmac: ~252 instrs per 4-entry group vs
// ~600. Same order, exact {0,1} values -> bit-identical. LDS 53KB, 2 blk/CU.
// ---------------------------------------------------------------------------
__global__ __launch_bounds__(256, 2) void h1_scan_a2(const float* __restrict__ PB1,
                                                     const float* __restrict__ W1,
                                                     const int* __restrict__ jlist0,
                                                     const unsigned long long* __restrict__ mask0,
                                                     const int* __restrict__ count0,
                                                     float* __restrict__ A2) {
    __shared__ alignas(16) float bitsf[256 * 52];   // [entry][t], stride 52 (16B-aligned rows)

    const int b   = blockIdx.x;
    const int tid = threadIdx.x;
    const int jc  = blockIdx.y * 256 + tid;

    float base = 0.f;
#pragma unroll
    for (int z = 0; z < 16; ++z) base += PB1[((size_t)z * BATCH + b) * N2 + jc];

    R50(DECLC)

    for (int c = 0; c < 8; ++c) {
        const int cnt      = count0[b * 8 + c];   // block-uniform
        const size_t lbase = (size_t)(b * 8 + c) * 256;
        if (cnt == 0) continue;                   // uniform branch — barrier-safe

        __syncthreads();   // previous chunk's readers done before overwrite
        // stage bits as floats: cnt*50 conversions split across 256 threads
        const int total = cnt * 50;
        for (int idx = tid; idx < total; idx += 256) {
            const int e = idx / 50;
            const int t = idx - e * 50;
            const unsigned long long mk = mask0[lbase + e];
            bitsf[e * 52 + t] = (float)((mk >> t) & 1ull);
        }
        __syncthreads();

        int e = 0;
        for (; e + 4 <= cnt; e += 4) {
            const int j0 = jlist0[lbase + e + 0];
            const int j1 = jlist0[lbase + e + 1];
            const int j2 = jlist0[lbase + e + 2];
            const int j3 = jlist0[lbase + e + 3];
            const float w0 = W1[(size_t)j0 * N2 + jc];
            const float w1 = W1[(size_t)j1 * N2 + jc];
            const float w2 = W1[(size_t)j2 * N2 + jc];
            const float w3 = W1[(size_t)j3 * N2 + jc];
            const int eo0 = (e + 0) * 52;
            const int eo1 = (e + 1) * 52;
            const int eo2 = (e + 2) * 52;
            const int eo3 = (e + 3) * 52;
            PQ4(0,1,2,3)    PQ4(4,5,6,7)    PQ4(8,9,10,11)  PQ4(12,13,14,15)
            PQ4(16,17,18,19) PQ4(20,21,22,23) PQ4(24,25,26,27) PQ4(28,29,30,31)
            PQ4(32,33,34,35) PQ4(36,37,38,39) PQ4(40,41,42,43) PQ4(44,45,46,47)
            {
                const float2 q0 = *(const float2*)&bitsf[eo0 + 48];
                const float2 q1 = *(const float2*)&bitsf[eo1 + 48];
                const float2 q2 = *(const float2*)&bitsf[eo2 + 48];
                const float2 q3 = *(const float2*)&bitsf[eo3 + 48];
                c48 += w0 * q0.x; c48 += w1 * q1.x; c48 += w2 * q2.x; c48 += w3 * q3.x;
                c49 += w0 * q0.y; c49 += w1 * q1.y; c49 += w2 * q2.y; c49 += w3 * q3.y;
            }
        }
        for (; e < cnt; ++e) {
            const int j   = jlist0[lbase + e];
            const float w = W1[(size_t)j * N2 + jc];
            const int eo  = e * 52;
            PS4(0,1,2,3)    PS4(4,5,6,7)    PS4(8,9,10,11)  PS4(12,13,14,15)
            PS4(16,17,18,19) PS4(20,21,22,23) PS4(24,25,26,27) PS4(28,29,30,31)
            PS4(32,33,34,35) PS4(36,37,38,39) PS4(40,41,42,43) PS4(44,45,46,47)
            {
                const float2 q = *(const float2*)&bitsf[eo + 48];
                c48 += w * q.x;
                c49 += w * q.y;
            }
        }
    }

    float s = 0.f, m = 0.f, a2 = 0.f;
    float pa = A50, pb = B50;
    const float inva = 1.0f / ALPHA, invb = 1.0f / BETA;
    R50(STEPT)

    A2[(size_t)b * N2 + jc] = a2;
}

// ---------------------------------------------------------------------------
// Sum 16 split-K partials of A2@W2 -> final output (128 x 512).
// ---------------------------------------------------------------------------
__global__ __launch_bounds__(256) void reduce_out(const float* __restrict__ PB2,
                                                  float* __restrict__ out) {
    const int idx = blockIdx.x * 256 + threadIdx.x;
    float v = 0.f;
#pragma unroll
    for (int z = 0; z < 16; ++z) v += PB2[(size_t)z * (BATCH * N3) + idx];
    out[idx] = v;
}

extern "C" void kernel_launch(void* const* d_in, const int* in_sizes, int n_in,
                              void* d_out, int out_size, void* d_ws, size_t ws_size,
                              hipStream_t stream) {
    const float* inputs = (const float*)d_in[0];   // (128, 1024)
    const float* W0     = (const float*)d_in[1];   // (1024, 2048)
    const float* W1     = (const float*)d_in[2];   // (2048, 2048)
    const float* W2     = (const float*)d_in[3];   // (2048, 512)
    float* out = (float*)d_out;                    // (128, 512)

    // workspace layout (~35 MB)
    float* P0  = (float*)d_ws;                         // 8 x 128 x 2048   fp32
    float* PB1 = P0 + 8 * BATCH * N1;                  // 16 x 128 x 2048  fp32
    float* A2  = PB1 + 16 * BATCH * N2;                // 128 x 2048       fp32
    float* PB2 = A2 + BATCH * N2;                      // 16 x 128 x 512   fp32
    unsigned long long* mk0 = (unsigned long long*)(PB2 + 16 * BATCH * N3);  // 128x8x256
    __hip_bfloat16* C0bf = (__hip_bfloat16*)(mk0 + BATCH * 8 * 256);         // 128 x 2048
    int* jl0  = (int*)(C0bf + (size_t)BATCH * N1);                           // 128 x 8 x 256
    int* cnt0 = jl0 + BATCH * 8 * 256;                                       // 128 x 8

    // 1. P0[z] = inputs @ W0 chunks   (128 x 1024 x 2048, split-K 8, fp32 —
    //    round-18 lesson: must stay fp32-exact)
    gemm_f32_splitk<<<dim3(N1 / 64, BATCH / 64, 8), 256, 0, stream>>>(
        inputs, W0, P0, BATCH, N1, N0, N0 / 8);

    // 2. layer-0 simulate + classify -> C0 (bf16), residual lists
    scan_l0_classify<<<dim3(BATCH, N1 / 256), 256, 0, stream>>>(P0, C0bf, jl0, mk0, cnt0);

    // 3. PB1[z] = C0 @ W1 chunks      (128 x 2048 x 2048, split-K 16, MFMA BN=64,
    //    W1 transpose + hi/lo split fused into B-staging)
    gemm3_bn64_fused<<<dim3(N2 / 64, 16), 256, 0, stream>>>(C0bf, W1, PB1, N1 / 16);

    // 4. fused layer-1 drive + scan + linear layer-2 projection -> A2
    h1_scan_a2<<<dim3(BATCH, N2 / 256), 256, 0, stream>>>(
        PB1, W1, jl0, mk0, cnt0, A2);

    // 5. PB2[z] = A2 @ W2 chunks      (128 x 2048 x 512, split-K 16, MFMA
    //    split-bf16 3-product — round 22)
    gemm2_mfma<<<dim3(N3 / 32, 16), 256, 0, stream>>>(A2, W2, PB2, N2 / 16);

    // 6. sum partials -> final membrane (128 x 512)
    reduce_out<<<(BATCH * N3) / 256, 256, 0, stream>>>(PB2, out);
}

// Round 11
// 133.019 us; speedup vs baseline: 1.1263x; 1.0401x over previous
//
#include <hip/hip_runtime.h>
#include <hip/hip_bf16.h>

#define ALPHA 0.9f
#define BETA  0.85f
#define TSIM  50
#define BATCH 128
#define N0    1024
#define N1    2048
#define N2    2048
#define N3    512

// alpha^50, beta^50, 1/(alpha-beta)
#define A50   0.00515379f
#define B50   0.000295764f
#define INVAB 20.0f

typedef __attribute__((ext_vector_type(8))) short bf16x8;
typedef __attribute__((ext_vector_type(8))) unsigned short ushort8;
typedef __attribute__((ext_vector_type(4))) float f32x4;

#define GLOBAL_AS __attribute__((address_space(1)))
#define LDS_AS    __attribute__((address_space(3)))

// preprocessor repeat lists (t = literal timestep)
#define R32(X) X(0) X(1) X(2) X(3) X(4) X(5) X(6) X(7) X(8) X(9) X(10) X(11) \
               X(12) X(13) X(14) X(15) X(16) X(17) X(18) X(19) X(20) X(21)   \
               X(22) X(23) X(24) X(25) X(26) X(27) X(28) X(29) X(30) X(31)
#define R18(X) X(32) X(33) X(34) X(35) X(36) X(37) X(38) X(39) X(40) X(41)   \
               X(42) X(43) X(44) X(45) X(46) X(47) X(48) X(49)
#define R50(X) R32(X) R18(X)

#define DECLC(t)   float c##t = 0.f;
// cvt probe form — the proven per-instruction floor. Lever scoreboard (7
// probes): batch-4 WIN; batch-8 ~; select-VGPR ✗(R7 +6.6); select-SGPR via
// readfirstlane ✗(R9 +15.6 — SALU does NOT co-issue with VALU from the same
// wave, instruction count is what matters); prefetch-1 ✗(R19); LDS list-stage
// ✗(R8 +2.2); LDS bit->float stage ✗(R10 +4.1, the 2 extra barriers/chunk
// cost more than shared cvt saves on ~26-entry avg lists). DO NOT revisit.
#define PROBELO(t) c##t += w * (float)((lo >> (t)) & 1u);
#define PROBEHI(t) c##t += w * (float)((hi >> ((t) - 32)) & 1u);
// batch-4 probes: addition order per c##t identical to serial (e ascending)
// -> bit-identical.
#define PROBE4LO(t) c##t += w0 * (float)((lo0 >> (t)) & 1u); \
                    c##t += w1 * (float)((lo1 >> (t)) & 1u); \
                    c##t += w2 * (float)((lo2 >> (t)) & 1u); \
                    c##t += w3 * (float)((lo3 >> (t)) & 1u);
#define PROBE4HI(t) c##t += w0 * (float)((hi0 >> ((t) - 32)) & 1u); \
                    c##t += w1 * (float)((hi1 >> ((t) - 32)) & 1u); \
                    c##t += w2 * (float)((hi2 >> ((t) - 32)) & 1u); \
                    c##t += w3 * (float)((hi3 >> ((t) - 32)) & 1u);
#define STEPT(t)                                                  \
    s = ALPHA * s + (base + c##t);                                \
    m = BETA * m + s;                                             \
    if (m - 1.f > 0.f) { a2 += (pa - pb) * INVAB; m = 0.f; }      \
    pa *= inva;                                                   \
    pb *= invb;

// ---------------------------------------------------------------------------
// Split-K fp32 tiled GEMM (layer 0 only). Round 16: do NOT lower split-K.
// Round 18: layer 0 must stay fp32-exact (split-bf16 -> absmax 636 fail).
// Round 22: float4 LDS reads (As [16][68], 2x ds_read_b128 per kk) — part of
// the verified 134.2 config.
// ---------------------------------------------------------------------------
__global__ __launch_bounds__(256) void gemm_f32_splitk(const float* __restrict__ A,
                                                       const float* __restrict__ B,
                                                       float* __restrict__ Cp,
                                                       int M, int N, int K, int KC) {
    __shared__ float As[16][68];
    __shared__ float Bs[16][68];

    const int tid = threadIdx.x;
    const int tx  = tid % 16;
    const int ty  = tid / 16;
    const int bx  = blockIdx.x;
    const int by  = blockIdx.y;
    const int z   = blockIdx.z;

    float acc[4][4] = {};

    const int ar = tid / 4;
    const int ak = (tid % 4) * 4;
    const int br = tid / 16;
    const int bc = (tid % 16) * 4;

    const int kbeg = z * KC;
    for (int k0 = kbeg; k0 < kbeg + KC; k0 += 16) {
        float4 av = *(const float4*)&A[(size_t)(by * 64 + ar) * K + k0 + ak];
        As[ak + 0][ar] = av.x;
        As[ak + 1][ar] = av.y;
        As[ak + 2][ar] = av.z;
        As[ak + 3][ar] = av.w;
        float4 bv = *(const float4*)&B[(size_t)(k0 + br) * N + bx * 64 + bc];
        *(float4*)&Bs[br][bc] = bv;
        __syncthreads();

#pragma unroll
        for (int kk = 0; kk < 16; ++kk) {
            const float4 a  = *(const float4*)&As[kk][ty * 4];
            const float4 bq = *(const float4*)&Bs[kk][tx * 4];
            const float a0 = a.x, a1 = a.y, a2 = a.z, a3 = a.w;
            const float b0 = bq.x, b1 = bq.y, b2 = bq.z, b3 = bq.w;
            acc[0][0] += a0 * b0; acc[0][1] += a0 * b1; acc[0][2] += a0 * b2; acc[0][3] += a0 * b3;
            acc[1][0] += a1 * b0; acc[1][1] += a1 * b1; acc[1][2] += a1 * b2; acc[1][3] += a1 * b3;
            acc[2][0] += a2 * b0; acc[2][1] += a2 * b1; acc[2][2] += a2 * b2; acc[2][3] += a2 * b3;
            acc[3][0] += a3 * b0; acc[3][1] += a3 * b1; acc[3][2] += a3 * b2; acc[3][3] += a3 * b3;
        }
        __syncthreads();
    }

#pragma unroll
    for (int i = 0; i < 4; ++i) {
        float4 v = make_float4(acc[i][0], acc[i][1], acc[i][2], acc[i][3]);
        *(float4*)&Cp[((size_t)z * M + by * 64 + ty * 4 + i) * N + bx * 64 + tx * 4] = v;
    }
}

// ---------------------------------------------------------------------------
// Layer-0 simulate + classify (sums 8 split-K partials; deterministic
// per-(b,chunk) residual lists via wave ballot + LDS wave-count scan).
// ---------------------------------------------------------------------------
__global__ __launch_bounds__(256) void scan_l0_classify(const float* __restrict__ P0,
                                                        __hip_bfloat16* __restrict__ C0,
                                                        int* __restrict__ jlist0,
                                                        unsigned long long* __restrict__ mask0,
                                                        int* __restrict__ count0) {
    const int b     = blockIdx.x;
    const int chunk = blockIdx.y;
    const int tid   = threadIdx.x;
    const int j     = chunk * 256 + tid;
    const int lane  = tid & 63;
    const int wv    = tid >> 6;

    float h = 0.f;
#pragma unroll
    for (int z = 0; z < 8; ++z) h += P0[((size_t)z * BATCH + b) * N1 + j];

    float m = 0.f;
    unsigned long long mask = 0ull;
#pragma unroll
    for (int t = 0; t < TSIM; ++t) {
        m = BETA * m + h;
        if (m - 1.f > 0.f) { mask |= (1ull << t); m = 0.f; }
    }
    const unsigned long long FULL = (1ull << TSIM) - 1ull;
    C0[(size_t)b * N1 + j] = __float2bfloat16((mask == FULL) ? 1.f : 0.f);

    const bool has = (mask != 0ull) && (mask != FULL);
    const unsigned long long bal = __ballot(has);

    __shared__ int wcnt[4];
    if (lane == 0) wcnt[wv] = __popcll(bal);
    __syncthreads();
    int base = 0;
#pragma unroll
    for (int w = 0; w < 4; ++w)
        if (w < wv) base += wcnt[w];
    const int pos = base + __popcll(bal & ((1ull << lane) - 1ull));

    const size_t lbase = (size_t)(b * 8 + chunk) * 256;
    if (has) {
        jlist0[lbase + pos] = j;
        mask0[lbase + pos]  = mask;
    }
    if (tid == 0) count0[b * 8 + chunk] = wcnt[0] + wcnt[1] + wcnt[2] + wcnt[3];
}

// ---------------------------------------------------------------------------
// MFMA GEMM (BN=64, BM=128=M, BK=32; 4 waves stacked in M; WMT=2, WNT=4):
// Cp[z] = C0 @ (W1h+W1l)^T, split-K 16 (KC=128, 512 blocks).
// W1 transpose + hi/lo split fused into B-staging (round 17, verified win).
// ---------------------------------------------------------------------------
__global__ __launch_bounds__(256) void gemm3_bn64_fused(const __hip_bfloat16* __restrict__ A,
                                                        const float* __restrict__ W, // (N1, N2) fp32
                                                        float* __restrict__ Cp, int KC) {
    __shared__ alignas(16) __hip_bfloat16 As[128 * 32];
    __shared__ alignas(16) __hip_bfloat16 Bhs[64 * 32];
    __shared__ alignas(16) __hip_bfloat16 Bls[64 * 32];

    constexpr int BK = 32;
    const int M = BATCH, N = N2, K = N1;

    const int tid  = threadIdx.x;
    const int wave = tid >> 6;
    const int lane = tid & 63;
    const int quad = lane >> 4;
    const int l16  = lane & 15;

    const int n0 = blockIdx.x * 64;
    const int z  = blockIdx.y;
    const int wm = wave * 32;

    f32x4 acc[2][4] = {};

    const __hip_bfloat16* agp[2];
    int aoff[2];
#pragma unroll
    for (int i = 0; i < 2; ++i) {
        const int c = i * 256 + tid;
        agp[i]  = A + (size_t)(c >> 2) * K + (c & 3) * 8;
        aoff[i] = c * 8;
    }

    // fused B staging: this thread owns col n0+bn, rows k0+bkb..k0+bkb+7
    const int bn  = tid >> 2;        // 0..63
    const int bkb = (tid & 3) * 8;   // 0,8,16,24

    const int kbeg = z * KC;
    for (int k0 = kbeg; k0 < kbeg + KC; k0 += BK) {
#pragma unroll
        for (int i = 0; i < 2; ++i)
            __builtin_amdgcn_global_load_lds((const GLOBAL_AS void*)(agp[i] + k0),
                                             (LDS_AS void*)&As[aoff[i]], 16, 0, 0);

        float wv[8];
#pragma unroll
        for (int u = 0; u < 8; ++u)
            wv[u] = W[(size_t)(k0 + bkb + u) * N + n0 + bn];

        ushort8 vh, vl;
#pragma unroll
        for (int u = 0; u < 8; ++u) {
            const float w = wv[u];
            const __hip_bfloat16 hi = __float2bfloat16(w);
            const float lo = w - __bfloat162float(hi);
            const __hip_bfloat16 lb = __float2bfloat16(lo);
            vh[u] = *(const unsigned short*)&hi;
            vl[u] = *(const unsigned short*)&lb;
        }
        *(ushort8*)&Bhs[bn * BK + bkb] = vh;
        *(ushort8*)&Bls[bn * BK + bkb] = vl;
        __syncthreads();

        bf16x8 af[2], bhf[4], blf[4];
#pragma unroll
        for (int i = 0; i < 2; ++i)
            af[i] = *(const bf16x8*)&As[(wm + i * 16 + l16) * BK + quad * 8];
#pragma unroll
        for (int j = 0; j < 4; ++j) {
            bhf[j] = *(const bf16x8*)&Bhs[(j * 16 + l16) * BK + quad * 8];
            blf[j] = *(const bf16x8*)&Bls[(j * 16 + l16) * BK + quad * 8];
        }
#pragma unroll
        for (int i = 0; i < 2; ++i)
#pragma unroll
            for (int j = 0; j < 4; ++j) {
                acc[i][j] = __builtin_amdgcn_mfma_f32_16x16x32_bf16(af[i], bhf[j], acc[i][j], 0, 0, 0);
                acc[i][j] = __builtin_amdgcn_mfma_f32_16x16x32_bf16(af[i], blf[j], acc[i][j], 0, 0, 0);
            }
        __syncthreads();
    }

    // C/D layout: col = lane&15, row = quad*4 + reg
#pragma unroll
    for (int i = 0; i < 2; ++i)
#pragma unroll
        for (int j = 0; j < 4; ++j)
#pragma unroll
            for (int r = 0; r < 4; ++r)
                Cp[((size_t)z * M + wm + i * 16 + quad * 4 + r) * N + n0 + j * 16 + l16] =
                    acc[i][j][r];
}

// ---------------------------------------------------------------------------
// Round 22: layer-2 GEMM MFMA split-bf16 3-product (verified pass, absmax 32).
// PB2[z] = A2 @ W2 chunk z. BM=128(=M), BN=32, BK=32, split-K 16, 256 blocks.
// ---------------------------------------------------------------------------
__global__ __launch_bounds__(256) void gemm2_mfma(const float* __restrict__ A,  // (128,2048)
                                                  const float* __restrict__ W,  // (2048,512)
                                                  float* __restrict__ Cp, int KC) {
    __shared__ alignas(16) __hip_bfloat16 Ahs[128 * 32];
    __shared__ alignas(16) __hip_bfloat16 Als[128 * 32];
    __shared__ alignas(16) __hip_bfloat16 Bhs[32 * 32];
    __shared__ alignas(16) __hip_bfloat16 Bls[32 * 32];

    constexpr int BK = 32;
    const int tid  = threadIdx.x;
    const int wave = tid >> 6;
    const int lane = tid & 63;
    const int quad = lane >> 4;
    const int l16  = lane & 15;

    const int n0 = blockIdx.x * 32;
    const int z  = blockIdx.y;
    const int wm = wave * 32;

    f32x4 acc[2][2] = {};

    const int ar = tid >> 1;
    const int ao = (tid & 1) * 16;
    const int bn = tid & 31;
    const int bq = (tid >> 5) * 4;

    const int kbeg = z * KC;
    for (int k0 = kbeg; k0 < kbeg + KC; k0 += BK) {
        float af[16];
#pragma unroll
        for (int q = 0; q < 4; ++q) {
            float4 v = *(const float4*)&A[(size_t)ar * N2 + k0 + ao + q * 4];
            af[q * 4 + 0] = v.x; af[q * 4 + 1] = v.y;
            af[q * 4 + 2] = v.z; af[q * 4 + 3] = v.w;
        }
#pragma unroll
        for (int h = 0; h < 2; ++h) {
            ushort8 vh, vl;
#pragma unroll
            for (int u = 0; u < 8; ++u) {
                const float a = af[h * 8 + u];
                const __hip_bfloat16 hi = __float2bfloat16(a);
                const float lo = a - __bfloat162float(hi);
                const __hip_bfloat16 lb = __float2bfloat16(lo);
                vh[u] = *(const unsigned short*)&hi;
                vl[u] = *(const unsigned short*)&lb;
            }
            *(ushort8*)&Ahs[ar * BK + ao + h * 8] = vh;
            *(ushort8*)&Als[ar * BK + ao + h * 8] = vl;
        }

        {
            float wf[4];
#pragma unroll
            for (int u = 0; u < 4; ++u)
                wf[u] = W[(size_t)(k0 + bq + u) * N3 + n0 + bn];
#pragma unroll
            for (int u = 0; u < 4; ++u) {
                const float w = wf[u];
                const __hip_bfloat16 hi = __float2bfloat16(w);
                const float lo = w - __bfloat162float(hi);
                const __hip_bfloat16 lb = __float2bfloat16(lo);
                Bhs[bn * BK + bq + u] = hi;
                Bls[bn * BK + bq + u] = lb;
            }
        }
        __syncthreads();

        bf16x8 ah[2], al[2], bh[2], bl[2];
#pragma unroll
        for (int i = 0; i < 2; ++i) {
            ah[i] = *(const bf16x8*)&Ahs[(wm + i * 16 + l16) * BK + quad * 8];
            al[i] = *(const bf16x8*)&Als[(wm + i * 16 + l16) * BK + quad * 8];
        }
#pragma unroll
        for (int j = 0; j < 2; ++j) {
            bh[j] = *(const bf16x8*)&Bhs[(j * 16 + l16) * BK + quad * 8];
            bl[j] = *(const bf16x8*)&Bls[(j * 16 + l16) * BK + quad * 8];
        }
#pragma unroll
        for (int i = 0; i < 2; ++i)
#pragma unroll
            for (int j = 0; j < 2; ++j) {
                acc[i][j] = __builtin_amdgcn_mfma_f32_16x16x32_bf16(ah[i], bh[j], acc[i][j], 0, 0, 0);
                acc[i][j] = __builtin_amdgcn_mfma_f32_16x16x32_bf16(ah[i], bl[j], acc[i][j], 0, 0, 0);
                acc[i][j] = __builtin_amdgcn_mfma_f32_16x16x32_bf16(al[i], bh[j], acc[i][j], 0, 0, 0);
            }
        __syncthreads();
    }

#pragma unroll
    for (int i = 0; i < 2; ++i)
#pragma unroll
        for (int j = 0; j < 2; ++j)
#pragma unroll
            for (int r = 0; r < 4; ++r)
                Cp[((size_t)z * BATCH + wm + i * 16 + quad * 4 + r) * N3 + n0 + j * 16 + l16] =
                    acc[i][j][r];
}

// ---------------------------------------------------------------------------
// Layer-1 fused drive + membrane scan + linear layer-2 projection.
// 50 named scalar accumulators + __launch_bounds__(256,2): do not lower.
// This is the R6-verified form (134.2us total): cvt probes + batch-4 gather,
// global lists. Structural floor per 7-probe scoreboard (see macro comment).
// ---------------------------------------------------------------------------
__global__ __launch_bounds__(256, 2) void h1_scan_a2(const float* __restrict__ PB1,
                                                     const float* __restrict__ W1,
                                                     const int* __restrict__ jlist0,
                                                     const unsigned long long* __restrict__ mask0,
                                                     const int* __restrict__ count0,
                                                     float* __restrict__ A2) {
    const int b  = blockIdx.x;
    const int jc = blockIdx.y * 256 + threadIdx.x;

    float base = 0.f;
#pragma unroll
    for (int z = 0; z < 16; ++z) base += PB1[((size_t)z * BATCH + b) * N2 + jc];

    R50(DECLC)

    for (int c = 0; c < 8; ++c) {
        const int cnt      = count0[b * 8 + c];
        const size_t lbase = (size_t)(b * 8 + c) * 256;
        int e = 0;
        for (; e + 4 <= cnt; e += 4) {
            const int j0 = jlist0[lbase + e + 0];
            const int j1 = jlist0[lbase + e + 1];
            const int j2 = jlist0[lbase + e + 2];
            const int j3 = jlist0[lbase + e + 3];
            const float w0 = W1[(size_t)j0 * N2 + jc];
            const float w1 = W1[(size_t)j1 * N2 + jc];
            const float w2 = W1[(size_t)j2 * N2 + jc];
            const float w3 = W1[(size_t)j3 * N2 + jc];
            const unsigned long long ma = mask0[lbase + e + 0];
            const unsigned long long mb = mask0[lbase + e + 1];
            const unsigned long long mc = mask0[lbase + e + 2];
            const unsigned long long md = mask0[lbase + e + 3];
            const unsigned lo0 = (unsigned)ma, hi0 = (unsigned)(ma >> 32);
            const unsigned lo1 = (unsigned)mb, hi1 = (unsigned)(mb >> 32);
            const unsigned lo2 = (unsigned)mc, hi2 = (unsigned)(mc >> 32);
            const unsigned lo3 = (unsigned)md, hi3 = (unsigned)(md >> 32);
            R32(PROBE4LO)
            R18(PROBE4HI)
        }
        for (; e < cnt; ++e) {
            const unsigned long long mk = mask0[lbase + e];
            const int j                 = jlist0[lbase + e];
            const float w               = W1[(size_t)j * N2 + jc];
            const unsigned lo = (unsigned)mk, hi = (unsigned)(mk >> 32);
            R32(PROBELO)
            R18(PROBEHI)
        }
    }

    float s = 0.f, m = 0.f, a2 = 0.f;
    float pa = A50, pb = B50;
    const float inva = 1.0f / ALPHA, invb = 1.0f / BETA;
    R50(STEPT)

    A2[(size_t)b * N2 + jc] = a2;
}

// ---------------------------------------------------------------------------
// Sum 16 split-K partials of A2@W2 -> final output (128 x 512).
// ---------------------------------------------------------------------------
__global__ __launch_bounds__(256) void reduce_out(const float* __restrict__ PB2,
                                                  float* __restrict__ out) {
    const int idx = blockIdx.x * 256 + threadIdx.x;
    float v = 0.f;
#pragma unroll
    for (int z = 0; z < 16; ++z) v += PB2[(size_t)z * (BATCH * N3) + idx];
    out[idx] = v;
}

extern "C" void kernel_launch(void* const* d_in, const int* in_sizes, int n_in,
                              void* d_out, int out_size, void* d_ws, size_t ws_size,
                              hipStream_t stream) {
    const float* inputs = (const float*)d_in[0];   // (128, 1024)
    const float* W0     = (const float*)d_in[1];   // (1024, 2048)
    const float* W1     = (const float*)d_in[2];   // (2048, 2048)
    const float* W2     = (const float*)d_in[3];   // (2048, 512)
    float* out = (float*)d_out;                    // (128, 512)

    // workspace layout (~35 MB)
    float* P0  = (float*)d_ws;                         // 8 x 128 x 2048   fp32
    float* PB1 = P0 + 8 * BATCH * N1;                  // 16 x 128 x 2048  fp32
    float* A2  = PB1 + 16 * BATCH * N2;                // 128 x 2048       fp32
    float* PB2 = A2 + BATCH * N2;                      // 16 x 128 x 512   fp32
    unsigned long long* mk0 = (unsigned long long*)(PB2 + 16 * BATCH * N3);  // 128x8x256
    __hip_bfloat16* C0bf = (__hip_bfloat16*)(mk0 + BATCH * 8 * 256);         // 128 x 2048
    int* jl0  = (int*)(C0bf + (size_t)BATCH * N1);                           // 128 x 8 x 256
    int* cnt0 = jl0 + BATCH * 8 * 256;                                       // 128 x 8

    // 1. P0[z] = inputs @ W0 chunks   (128 x 1024 x 2048, split-K 8, fp32 —
    //    round-18 lesson: must stay fp32-exact)
    gemm_f32_splitk<<<dim3(N1 / 64, BATCH / 64, 8), 256, 0, stream>>>(
        inputs, W0, P0, BATCH, N1, N0, N0 / 8);

    // 2. layer-0 simulate + classify -> C0 (bf16), residual lists
    scan_l0_classify<<<dim3(BATCH, N1 / 256), 256, 0, stream>>>(P0, C0bf, jl0, mk0, cnt0);

    // 3. PB1[z] = C0 @ W1 chunks      (128 x 2048 x 2048, split-K 16, MFMA BN=64,
    //    W1 transpose + hi/lo split fused into B-staging)
    gemm3_bn64_fused<<<dim3(N2 / 64, 16), 256, 0, stream>>>(C0bf, W1, PB1, N1 / 16);

    // 4. fused layer-1 drive + scan + linear layer-2 projection -> A2
    h1_scan_a2<<<dim3(BATCH, N2 / 256), 256, 0, stream>>>(
        PB1, W1, jl0, mk0, cnt0, A2);

    // 5. PB2[z] = A2 @ W2 chunks      (128 x 2048 x 512, split-K 16, MFMA
    //    split-bf16 3-product — round 22)
    gemm2_mfma<<<dim3(N3 / 32, 16), 256, 0, stream>>>(A2, W2, PB2, N2 / 16);

    // 6. sum partials -> final membrane (128 x 512)
    reduce_out<<<(BATCH * N3) / 256, 256, 0, stream>>>(PB2, out);
}